// Round 4
// baseline (1344.082 us; speedup 1.0000x reference)
//
#include <hip/hip_runtime.h>
#include <stdint.h>

// W4A16 dequant-GEMM: out[M,N] = x[M,K] @ W[N,K]^T, fp32 out.
// HARNESS DTYPES (deduced R2): jnp.float16 inputs are delivered as FP32
// (harness supports only bf16/f32/int). x: f32[4096,4096], scales:
// f32[11008,32], qweight/qzeros: int32 (one byte each), out: f32[4096,11008].
// W[n,k] = (nibble - zero(group)) * scale(group), group=128 along K.

#define M_DIM 4096
#define N_DIM 11008
#define K_DIM 4096
#define BM 128
#define BN 128
#define BK 32
#define LDAB 40  // padded LDS row (halves): byte stride 80 (16B-aligned rows)

typedef _Float16 half8 __attribute__((ext_vector_type(8)));
typedef float floatx4 __attribute__((ext_vector_type(4)));

// pack two f32 -> two f16 (RTZ), as uint32 bits (v_cvt_pkrtz_f16_f32)
__device__ __forceinline__ uint32_t pk16(float a, float b) {
    return __builtin_bit_cast(uint32_t, __builtin_amdgcn_cvt_pkrtz(a, b));
}

// dequant one packed byte -> two fp16 weights (packed u32).
// w = fma(nibble, s, -z*s) in fp32 (exact nibble cvt, one fp32 round),
// then RTZ pack to fp16 (error << threshold budget).
__device__ __forceinline__ uint32_t dq2f(uint32_t v, float sf, float nzs) {
    float wl = fmaf((float)(v & 15u), sf, nzs);
    float wh = fmaf((float)((v >> 4) & 15u), sf, nzs);
    return pk16(wl, wh);
}

__global__ __launch_bounds__(256) void w4a16_gemm(
    const float* __restrict__ X,    // f32 [M,K]
    const int* __restrict__ QW,     // [N, K/2] one byte (2 nibbles) per int32
    const float* __restrict__ SC,   // f32 [N, 32]
    const int* __restrict__ QZ,     // [N, 16] one byte (2 group-zeros) per int32
    float* __restrict__ OUT)        // f32 [M, N]
{
    const int tid  = threadIdx.x;
    const int lane = tid & 63;
    const int wave = tid >> 6;
    const int wm = wave & 1;
    const int wn = wave >> 1;

    const int nblk = blockIdx.x;  // 86
    const int mblk = blockIdx.y;  // 32

    __shared__ alignas(16) _Float16 As[BM][LDAB];  // 10 KB
    __shared__ alignas(16) _Float16 Bs[BN][LDAB];  // 10 KB

    // ---- A staging map: 128 rows x 32 f32 = 1024 16B-chunks; 4 per thread.
    // chunk c: row=c>>3, sub=c&7 (4 floats each).
    const float* gA[4];
    _Float16* lA[4];
#pragma unroll
    for (int i = 0; i < 4; ++i) {
        const int c = tid + 256 * i;
        const int row = c >> 3, sub = c & 7;
        gA[i] = X + (size_t)(mblk * BM + row) * K_DIM + sub * 4;
        lA[i] = &As[row][sub * 4];
    }

    // ---- B staging map: 128 rows x 16 int32 = 512 16B-chunks; 2 per thread.
    const int r0 = tid >> 2, q0 = tid & 3;       // rows 0..63
    const int r1 = r0 + 64;                      // rows 64..127
    const int* gB0 = QW + (size_t)(nblk * BN + r0) * (K_DIM / 2) + q0 * 4;
    const int* gB1 = QW + (size_t)(nblk * BN + r1) * (K_DIM / 2) + q0 * 4;
    const float* sc0 = SC + (size_t)(nblk * BN + r0) * 32;
    const float* sc1 = SC + (size_t)(nblk * BN + r1) * 32;
    const int* qz0 = QZ + (size_t)(nblk * BN + r0) * 16;
    const int* qz1 = QZ + (size_t)(nblk * BN + r1) * 16;

    floatx4 acc[4][4] = {};

    const int fr = lane & 15;        // m (A frag) / n (B frag) within 16
    const int k8 = (lane >> 4) * 8;  // k offset of the 8-elem fragment

    for (int g = 0; g < 32; ++g) {
        const uint32_t zw0 = (uint32_t)qz0[g >> 1];
        const uint32_t zw1 = (uint32_t)qz1[g >> 1];
        const float zf0 = (float)((g & 1) ? ((zw0 >> 4) & 15u) : (zw0 & 15u));
        const float zf1 = (float)((g & 1) ? ((zw1 >> 4) & 15u) : (zw1 & 15u));
        const float sf0 = sc0[g];
        const float sf1 = sc1[g];
        const float nzs0 = -zf0 * sf0;
        const float nzs1 = -zf1 * sf1;

#pragma unroll
        for (int kk = 0; kk < 4; ++kk) {
            const int kt = (g << 2) | kk;

            // global loads first (let the compiler hoist/overlap)
            float4 av[4];
#pragma unroll
            for (int i = 0; i < 4; ++i)
                av[i] = *(const float4*)(gA[i] + (size_t)kt * BK);
            int4 p0 = *(const int4*)(gB0 + kt * 16);
            int4 p1 = *(const int4*)(gB1 + kt * 16);

            // convert A: f32 -> f16 (RTZ pack)
            uint2 wa[4];
#pragma unroll
            for (int i = 0; i < 4; ++i) {
                wa[i].x = pk16(av[i].x, av[i].y);
                wa[i].y = pk16(av[i].z, av[i].w);
            }
            // dequant B: byte -> 2 fp16 weights
            uint4 b0, b1;
            b0.x = dq2f((uint32_t)p0.x, sf0, nzs0);
            b0.y = dq2f((uint32_t)p0.y, sf0, nzs0);
            b0.z = dq2f((uint32_t)p0.z, sf0, nzs0);
            b0.w = dq2f((uint32_t)p0.w, sf0, nzs0);
            b1.x = dq2f((uint32_t)p1.x, sf1, nzs1);
            b1.y = dq2f((uint32_t)p1.y, sf1, nzs1);
            b1.z = dq2f((uint32_t)p1.z, sf1, nzs1);
            b1.w = dq2f((uint32_t)p1.w, sf1, nzs1);

#pragma unroll
            for (int i = 0; i < 4; ++i)
                *(uint2*)lA[i] = wa[i];
            *(uint4*)&Bs[r0][q0 * 8] = b0;
            *(uint4*)&Bs[r1][q0 * 8] = b1;
            __syncthreads();

            half8 a[4], b[4];
#pragma unroll
            for (int i = 0; i < 4; ++i) {
                a[i] = *(const half8*)&As[wm * 64 + i * 16 + fr][k8];
                b[i] = *(const half8*)&Bs[wn * 64 + i * 16 + fr][k8];
            }
#pragma unroll
            for (int i = 0; i < 4; ++i)
#pragma unroll
                for (int j = 0; j < 4; ++j)
                    acc[i][j] = __builtin_amdgcn_mfma_f32_16x16x32_f16(
                        a[i], b[j], acc[i][j], 0, 0, 0);
            __syncthreads();
        }
    }

    // epilogue: C/D layout col(n)=lane&15, row(m)=(lane>>4)*4+r  [m89-verified]
    const int m0 = mblk * BM + wm * 64 + ((lane >> 4) << 2);
    const int n0 = nblk * BN + wn * 64 + fr;
#pragma unroll
    for (int i = 0; i < 4; ++i)
#pragma unroll
        for (int j = 0; j < 4; ++j)
#pragma unroll
            for (int r = 0; r < 4; ++r)
                OUT[(size_t)(m0 + i * 16 + r) * N_DIM + (n0 + j * 16)] = acc[i][j][r];
}

extern "C" void kernel_launch(void* const* d_in, const int* in_sizes, int n_in,
                              void* d_out, int out_size, void* d_ws, size_t ws_size,
                              hipStream_t stream) {
    const float* X  = (const float*)d_in[0];
    const int*   QW = (const int*)d_in[1];
    const float* SC = (const float*)d_in[2];
    const int*   QZ = (const int*)d_in[3];
    float*       OUT = (float*)d_out;
    dim3 grid(N_DIM / BN, M_DIM / BM);
    w4a16_gemm<<<grid, dim3(256, 1, 1), 0, stream>>>(X, QW, SC, QZ, OUT);
}